// Round 4
// baseline (108.513 us; speedup 1.0000x reference)
//
#include <hip/hip_runtime.h>
#include <hip/hip_bf16.h>

#define BB 4
#define LL 1024
#define DIMD 512
#define HH 8
#define EHD 64
#define NBUCK 1023

using f32x4 = __attribute__((ext_vector_type(4))) float;
using s16x8 = __attribute__((ext_vector_type(8))) short;

__device__ __forceinline__ ushort to_bf16(float x) {
    union { float f; unsigned u; } v; v.f = x;
    unsigned r = (v.u + 0x7FFFu + ((v.u >> 16) & 1u)) >> 16;
    return (ushort)r;
}

__device__ __forceinline__ void gl_lds16(const ushort* g, ushort* l) {
    __builtin_amdgcn_global_load_lds(
        (const __attribute__((address_space(1))) unsigned int*)g,
        (__attribute__((address_space(3))) unsigned int*)l, 16, 0, 0);
}

// ---------------------------------------------------------------------------
// bf16 conversion of x, W_in, W_out
// ---------------------------------------------------------------------------
#define XN  2097152
#define WIN 786432
#define WON 262144
__global__ __launch_bounds__(256) void cvt_bf16(const float* __restrict__ x,
                                                const float* __restrict__ wi,
                                                const float* __restrict__ wo,
                                                ushort* __restrict__ xb,
                                                ushort* __restrict__ wib,
                                                ushort* __restrict__ wob)
{
    int idx = (blockIdx.x * 256 + threadIdx.x) * 4;
    const float* src; ushort* dst; int off;
    if (idx < XN)            { src = x;  dst = xb;  off = idx; }
    else if (idx < XN + WIN) { src = wi; dst = wib; off = idx - XN; }
    else                     { src = wo; dst = wob; off = idx - XN - WIN; }
    float4 v = *(const float4*)&src[off];
    ushort4 o;
    o.x = to_bf16(v.x); o.y = to_bf16(v.y);
    o.z = to_bf16(v.z); o.w = to_bf16(v.w);
    *(ushort4*)&dst[off] = o;
}

// ---------------------------------------------------------------------------
// MFMA GEMM (unchanged from round 3)
// ---------------------------------------------------------------------------
template<int BN, int WMODE>
__global__ __launch_bounds__(256) void mfma_gemm(const ushort* __restrict__ A,
                                                 const ushort* __restrict__ B,
                                                 const float* __restrict__ bias,
                                                 float* __restrict__ outf,
                                                 ushort* __restrict__ outq,
                                                 ushort* __restrict__ outk,
                                                 ushort* __restrict__ outv,
                                                 const int* __restrict__ time_ids,
                                                 int M, int N, int K)
{
    constexpr int NREP = BN / 32;
    constexpr int SMEM_SZ = (WMODE == 1) ? 34816 : (16384 + BN * 128);
    __shared__ __align__(16) char smem[SMEM_SZ];
    ushort* Abuf = (ushort*)smem;
    ushort* Bbuf = (ushort*)(smem + 16384);

    const int t = threadIdx.x;
    const int lane = t & 63;
    const int w = t >> 6;
    const int l15 = lane & 15, lg = lane >> 4;
    const int wr = w >> 1, wc = w & 1;
    const int m0 = blockIdx.x * 128;
    const int n0 = blockIdx.y * BN;

    const int asub = lane >> 3;
    const int kc8 = (lane & 7) * 8;
    const int arow_base = w * 32;
    const int brow_base = w * (BN / 4);

    f32x4 acc[4][NREP];
    #pragma unroll
    for (int mf = 0; mf < 4; ++mf)
        #pragma unroll
        for (int nf = 0; nf < NREP; ++nf)
            acc[mf][nf] = {0.f, 0.f, 0.f, 0.f};

    for (int k0 = 0; k0 < K; k0 += 64) {
        #pragma unroll
        for (int i = 0; i < 4; ++i) {
            int row = arow_base + i * 8;
            gl_lds16(&A[(size_t)(m0 + row + asub) * K + k0 + kc8], &Abuf[row * 64]);
        }
        #pragma unroll
        for (int i = 0; i < BN / 32; ++i) {
            int row = brow_base + i * 8;
            gl_lds16(&B[(size_t)(n0 + row + asub) * K + k0 + kc8], &Bbuf[row * 64]);
        }
        __syncthreads();
        #pragma unroll
        for (int kk = 0; kk < 2; ++kk) {
            s16x8 af[4], bf[NREP];
            #pragma unroll
            for (int mf = 0; mf < 4; ++mf)
                af[mf] = *(const s16x8*)&Abuf[(wr * 64 + mf * 16 + l15) * 64 + kk * 32 + lg * 8];
            #pragma unroll
            for (int nf = 0; nf < NREP; ++nf)
                bf[nf] = *(const s16x8*)&Bbuf[(wc * (BN / 2) + nf * 16 + l15) * 64 + kk * 32 + lg * 8];
            #pragma unroll
            for (int mf = 0; mf < 4; ++mf)
                #pragma unroll
                for (int nf = 0; nf < NREP; ++nf)
                    acc[mf][nf] = __builtin_amdgcn_mfma_f32_16x16x32_bf16(af[mf], bf[nf], acc[mf][nf], 0, 0, 0);
        }
        __syncthreads();
    }

    if (WMODE == 0) {
        float bv[NREP];
        #pragma unroll
        for (int nf = 0; nf < NREP; ++nf) bv[nf] = bias[n0 + wc * (BN / 2) + nf * 16 + l15];
        #pragma unroll
        for (int mf = 0; mf < 4; ++mf)
            #pragma unroll
            for (int r = 0; r < 4; ++r) {
                int m = m0 + wr * 64 + mf * 16 + lg * 4 + r;
                #pragma unroll
                for (int nf = 0; nf < NREP; ++nf)
                    outf[(size_t)m * N + n0 + wc * (BN / 2) + nf * 16 + l15] = acc[mf][nf][r] + bv[nf];
            }
    } else {
        const int which = n0 >> 9;
        if (which < 2) {
            const int h = ((n0 & 511) + wc * 64) >> 6;
            ushort* dst = (which == 0) ? outq : outk;
            float bv[4];
            #pragma unroll
            for (int nf = 0; nf < 4; ++nf) bv[nf] = bias[n0 + wc * 64 + nf * 16 + l15];
            const float L2T = 13.287712379549449f;  // log2(10000)
            float inv0 = exp2f(-(float)(l15)      * (L2T / 32.f));
            float inv1 = exp2f(-(float)(16 + l15) * (L2T / 32.f));
            #pragma unroll
            for (int mf = 0; mf < 4; ++mf)
                #pragma unroll
                for (int r = 0; r < 4; ++r) {
                    int m = m0 + wr * 64 + mf * 16 + lg * 4 + r;
                    int b = m >> 10, li = m & (LL - 1);
                    int tt = time_ids[b * LL + li];
                    size_t rowbase = (((size_t)(b * HH + h)) * LL + li) * EHD;
                    #pragma unroll
                    for (int nf = 0; nf < 2; ++nf) {
                        float ang = (float)tt * (nf ? inv1 : inv0);
                        float c, s;
                        sincosf(ang, &s, &c);
                        float v1 = acc[mf][nf][r] + bv[nf];
                        float v2 = acc[mf][nf + 2][r] + bv[nf + 2];
                        dst[rowbase + nf * 16 + l15]      = to_bf16(v1 * c - v2 * s);
                        dst[rowbase + 32 + nf * 16 + l15] = to_bf16(v2 * c + v1 * s);
                    }
                }
        } else {
            ushort* T = (ushort*)smem;   // [128][136]
            float bv[4];
            #pragma unroll
            for (int nf = 0; nf < 4; ++nf) bv[nf] = bias[n0 + wc * 64 + nf * 16 + l15];
            #pragma unroll
            for (int mf = 0; mf < 4; ++mf)
                #pragma unroll
                for (int nf = 0; nf < 4; ++nf) {
                    int n = wc * 64 + nf * 16 + l15;
                    int mb = wr * 64 + mf * 16 + lg * 4;
                    ushort4 pk;
                    pk.x = to_bf16(acc[mf][nf][0] + bv[nf]);
                    pk.y = to_bf16(acc[mf][nf][1] + bv[nf]);
                    pk.z = to_bf16(acc[mf][nf][2] + bv[nf]);
                    pk.w = to_bf16(acc[mf][nf][3] + bv[nf]);
                    *(ushort4*)&T[n * 136 + mb] = pk;
                }
            __syncthreads();
            const int b = m0 >> 10, li0 = m0 & (LL - 1);
            const int hbase = (n0 & 511) >> 6;
            #pragma unroll
            for (int it = 0; it < 8; ++it) {
                int n = it * 16 + (t >> 4);
                int mc = (t & 15) * 8;
                uint4 val = *(const uint4*)&T[n * 136 + mc];
                int h = hbase + (n >> 6);
                int e = n & 63;
                *(uint4*)&outv[(((size_t)(b * HH + h)) * EHD + e) * LL + li0 + mc] = val;
            }
        }
    }
}

// ---------------------------------------------------------------------------
// Barrier-free MFMA attention. Block = 4 independent waves, each owns 16
// q-rows. K/V fragments read directly from global (L2-resident panels).
// PB (post-bias) A-fragments computed directly from time_ids (no LDS bounce).
// Softmax in log2 domain. Only P bounces via wave-private swizzled LDS.
// ---------------------------------------------------------------------------
__global__ __launch_bounds__(256) void attn_mfma(const ushort* __restrict__ qb,
                                                 const ushort* __restrict__ kb,
                                                 const ushort* __restrict__ vt,
                                                 const int* __restrict__ time_ids,
                                                 const float* __restrict__ rel_table,
                                                 const float* __restrict__ post_table,
                                                 ushort* __restrict__ ao)
{
    __shared__ __align__(16) float rt_s[1024];      // pre-scaled by log2(e)
    __shared__ __align__(16) float pt_s[1024];      // raw
    __shared__ __align__(16) ushort Ps[4][1024];    // per-wave P bounce, swizzled

    const int t = threadIdx.x;
    const int lane = t & 63;
    const int w = t >> 6;
    const int l15 = lane & 15, lg = lane >> 4;
    const int bh = blockIdx.x, b = bh >> 3, h = bh & 7;
    const int wq0 = blockIdx.y * 64 + w * 16;

    const float L2E = 1.4426950408889634f;
    for (int i = t; i < NBUCK; i += 256) {
        rt_s[i] = rel_table[h * NBUCK + i] * L2E;
        pt_s[i] = post_table[h * NBUCK + i];
    }

    const ushort* qpan = qb + (size_t)bh * LL * EHD;
    const ushort* kpan = kb + (size_t)bh * LL * EHD;
    const ushort* vpan = vt + (size_t)bh * EHD * LL;
    const int* tid_b = time_ids + b * LL;

    s16x8 qf[2];
    #pragma unroll
    for (int ec = 0; ec < 2; ++ec)
        qf[ec] = *(const s16x8*)&qpan[(size_t)(wq0 + l15) * EHD + ec * 32 + lg * 8];

    int4 tq4 = *(const int4*)&tid_b[wq0 + lg * 4];
    const int tqC[4] = {tq4.x + 511, tq4.y + 511, tq4.z + 511, tq4.w + 511};
    const int tqA = tid_b[wq0 + l15] + 511;

    __syncthreads();   // tables ready; the only block-wide barrier

    float mrow[4], drow[4];
    f32x4 acc1[4], acc2[4];
    #pragma unroll
    for (int r = 0; r < 4; ++r) { mrow[r] = -1e30f; drow[r] = 0.f; }
    #pragma unroll
    for (int ei = 0; ei < 4; ++ei) {
        acc1[ei] = {0.f, 0.f, 0.f, 0.f};
        acc2[ei] = {0.f, 0.f, 0.f, 0.f};
    }

    ushort* ps = Ps[w];

    for (int kt = 0; kt < 16; ++kt) {
        const int k0 = kt * 64;

        // ---- QK^T: K B-fragments straight from L2 ----
        f32x4 sc[4];
        #pragma unroll
        for (int ci = 0; ci < 4; ++ci) sc[ci] = {0.f, 0.f, 0.f, 0.f};
        s16x8 kf[4][2];
        #pragma unroll
        for (int ci = 0; ci < 4; ++ci)
            #pragma unroll
            for (int ec = 0; ec < 2; ++ec)
                kf[ci][ec] = *(const s16x8*)&kpan[(size_t)(k0 + ci * 16 + l15) * EHD + ec * 32 + lg * 8];
        #pragma unroll
        for (int ec = 0; ec < 2; ++ec)
            #pragma unroll
            for (int ci = 0; ci < 4; ++ci)
                sc[ci] = __builtin_amdgcn_mfma_f32_16x16x32_bf16(qf[ec], kf[ci][ec], sc[ci], 0, 0, 0);

        // ---- V B-fragments from L2 (shared by PB and P passes) ----
        s16x8 vf[4][2];
        #pragma unroll
        for (int ei = 0; ei < 4; ++ei)
            #pragma unroll
            for (int kk = 0; kk < 2; ++kk)
                vf[ei][kk] = *(const s16x8*)&vpan[(size_t)(ei * 16 + l15) * LL + k0 + kk * 32 + lg * 8];

        // ---- PB A-fragments directly from time_ids + table (no bounce) ----
        #pragma unroll
        for (int kk = 0; kk < 2; ++kk) {
            int4 ta = *(const int4*)&tid_b[k0 + kk * 32 + lg * 8];
            int4 tb = *(const int4*)&tid_b[k0 + kk * 32 + lg * 8 + 4];
            int tk8[8] = {ta.x, ta.y, ta.z, ta.w, tb.x, tb.y, tb.z, tb.w};
            s16x8 pb;
            #pragma unroll
            for (int j = 0; j < 8; ++j)
                pb[j] = (short)to_bf16(pt_s[tqA - tk8[j]]);
            #pragma unroll
            for (int ei = 0; ei < 4; ++ei)
                acc2[ei] = __builtin_amdgcn_mfma_f32_16x16x32_bf16(pb, vf[ei][kk], acc2[ei], 0, 0, 0);
        }

        // ---- rel-bias add (log2 domain) ----
        int tkC[4];
        #pragma unroll
        for (int ci = 0; ci < 4; ++ci) tkC[ci] = tid_b[k0 + ci * 16 + l15];
        #pragma unroll
        for (int ci = 0; ci < 4; ++ci)
            #pragma unroll
            for (int r = 0; r < 4; ++r)
                sc[ci][r] = sc[ci][r] * 0.18033688011111793f + rt_s[tqC[r] - tkC[ci]];

        // ---- online softmax (base-2), P -> wave-private LDS ----
        #pragma unroll
        for (int r = 0; r < 4; ++r) {
            float mx = fmaxf(fmaxf(sc[0][r], sc[1][r]), fmaxf(sc[2][r], sc[3][r]));
            #pragma unroll
            for (int d = 1; d < 16; d <<= 1) mx = fmaxf(mx, __shfl_xor(mx, d));
            float mnew = fmaxf(mrow[r], mx);
            float fs = exp2f(mrow[r] - mnew);
            mrow[r] = mnew;
            float rsum = 0.f;
            #pragma unroll
            for (int ci = 0; ci < 4; ++ci) {
                float p = exp2f(sc[ci][r] - mnew);
                sc[ci][r] = p;
                rsum += p;
            }
            #pragma unroll
            for (int d = 1; d < 16; d <<= 1) rsum += __shfl_xor(rsum, d);
            drow[r] = drow[r] * fs + rsum;
            #pragma unroll
            for (int ei = 0; ei < 4; ++ei) acc1[ei][r] *= fs;
            int row = lg * 4 + r;
            #pragma unroll
            for (int ci = 0; ci < 4; ++ci)
                *(ushort*)((char*)ps + row * 128 + ((ci * 32 + l15 * 2) ^ ((row & 7) << 4)))
                    = to_bf16(sc[ci][r]);
        }

        // ---- P @ V ----
        #pragma unroll
        for (int kk = 0; kk < 2; ++kk) {
            s16x8 af = *(const s16x8*)((const char*)ps + l15 * 128 +
                                       ((kk * 64 + lg * 16) ^ ((l15 & 7) << 4)));
            #pragma unroll
            for (int ei = 0; ei < 4; ++ei)
                acc1[ei] = __builtin_amdgcn_mfma_f32_16x16x32_bf16(af, vf[ei][kk], acc1[ei], 0, 0, 0);
        }
    }

    #pragma unroll
    for (int ei = 0; ei < 4; ++ei) {
        #pragma unroll
        for (int r = 0; r < 4; ++r) {
            int row = wq0 + lg * 4 + r;
            int col = h * EHD + ei * 16 + l15;
            ao[(size_t)(b * LL + row) * DIMD + col] = to_bf16(acc1[ei][r] / drow[r] + acc2[ei][r]);
        }
    }
}

extern "C" void kernel_launch(void* const* d_in, const int* in_sizes, int n_in,
                              void* d_out, int out_size, void* d_ws, size_t ws_size,
                              hipStream_t stream)
{
    const float* x        = (const float*)d_in[0];
    const int*   time_ids = (const int*)d_in[2];
    const float* W_in     = (const float*)d_in[3];
    const float* b_in     = (const float*)d_in[4];
    const float* W_out    = (const float*)d_in[5];
    const float* b_out    = (const float*)d_in[6];
    const float* rel_t    = (const float*)d_in[7];
    const float* post_t   = (const float*)d_in[8];
    float* out = (float*)d_out;

    ushort* wsu = (ushort*)d_ws;
    ushort* xb  = wsu;
    ushort* wib = xb + XN;
    ushort* wob = wib + WIN;
    ushort* qbf = wob + WON;
    ushort* kbf = qbf + XN;
    ushort* vtb = kbf + XN;
    ushort* aob = vtb + XN;

    cvt_bf16<<<3072, 256, 0, stream>>>(x, W_in, W_out, xb, wib, wob);
    mfma_gemm<128, 1><<<dim3(32, 12), 256, 0, stream>>>(xb, wib, b_in,
                                                        nullptr, qbf, kbf, vtb,
                                                        time_ids,
                                                        BB * LL, 3 * DIMD, DIMD);
    attn_mfma<<<dim3(32, 16), 256, 0, stream>>>(qbf, kbf, vtb, time_ids,
                                                rel_t, post_t, aob);
    mfma_gemm<64, 0><<<dim3(32, 8), 256, 0, stream>>>(aob, wob, b_out,
                                                      out, nullptr, nullptr, nullptr,
                                                      nullptr,
                                                      BB * LL, DIMD, DIMD);
}

// Round 5
// 85.305 us; speedup vs baseline: 1.2721x; 1.2721x over previous
//
#include <hip/hip_runtime.h>
#include <hip/hip_bf16.h>

#define BB 4
#define LL 1024
#define DIMD 512
#define HH 8
#define EHD 64
#define NBUCK 1023

using f32x4 = __attribute__((ext_vector_type(4))) float;
using s16x8 = __attribute__((ext_vector_type(8))) short;

__device__ __forceinline__ ushort to_bf16(float x) {
    union { float f; unsigned u; } v; v.f = x;
    unsigned r = (v.u + 0x7FFFu + ((v.u >> 16) & 1u)) >> 16;
    return (ushort)r;
}

__device__ __forceinline__ void gl_lds16(const ushort* g, ushort* l) {
    __builtin_amdgcn_global_load_lds(
        (const __attribute__((address_space(1))) unsigned int*)g,
        (__attribute__((address_space(3))) unsigned int*)l, 16, 0, 0);
}

// ---------------------------------------------------------------------------
// bf16 conversion of x, W_in, W_out
// ---------------------------------------------------------------------------
#define XN  2097152
#define WIN 786432
#define WON 262144
__global__ __launch_bounds__(256) void cvt_bf16(const float* __restrict__ x,
                                                const float* __restrict__ wi,
                                                const float* __restrict__ wo,
                                                ushort* __restrict__ xb,
                                                ushort* __restrict__ wib,
                                                ushort* __restrict__ wob)
{
    int idx = (blockIdx.x * 256 + threadIdx.x) * 4;
    const float* src; ushort* dst; int off;
    if (idx < XN)            { src = x;  dst = xb;  off = idx; }
    else if (idx < XN + WIN) { src = wi; dst = wib; off = idx - XN; }
    else                     { src = wo; dst = wob; off = idx - XN - WIN; }
    float4 v = *(const float4*)&src[off];
    ushort4 o;
    o.x = to_bf16(v.x); o.y = to_bf16(v.y);
    o.z = to_bf16(v.z); o.w = to_bf16(v.w);
    *(ushort4*)&dst[off] = o;
}

// ---------------------------------------------------------------------------
// MFMA GEMM (unchanged from round 3)
// ---------------------------------------------------------------------------
template<int BN, int WMODE>
__global__ __launch_bounds__(256) void mfma_gemm(const ushort* __restrict__ A,
                                                 const ushort* __restrict__ B,
                                                 const float* __restrict__ bias,
                                                 float* __restrict__ outf,
                                                 ushort* __restrict__ outq,
                                                 ushort* __restrict__ outk,
                                                 ushort* __restrict__ outv,
                                                 const int* __restrict__ time_ids,
                                                 int M, int N, int K)
{
    constexpr int NREP = BN / 32;
    constexpr int SMEM_SZ = (WMODE == 1) ? 34816 : (16384 + BN * 128);
    __shared__ __align__(16) char smem[SMEM_SZ];
    ushort* Abuf = (ushort*)smem;
    ushort* Bbuf = (ushort*)(smem + 16384);

    const int t = threadIdx.x;
    const int lane = t & 63;
    const int w = t >> 6;
    const int l15 = lane & 15, lg = lane >> 4;
    const int wr = w >> 1, wc = w & 1;
    const int m0 = blockIdx.x * 128;
    const int n0 = blockIdx.y * BN;

    const int asub = lane >> 3;
    const int kc8 = (lane & 7) * 8;
    const int arow_base = w * 32;
    const int brow_base = w * (BN / 4);

    f32x4 acc[4][NREP];
    #pragma unroll
    for (int mf = 0; mf < 4; ++mf)
        #pragma unroll
        for (int nf = 0; nf < NREP; ++nf)
            acc[mf][nf] = {0.f, 0.f, 0.f, 0.f};

    for (int k0 = 0; k0 < K; k0 += 64) {
        #pragma unroll
        for (int i = 0; i < 4; ++i) {
            int row = arow_base + i * 8;
            gl_lds16(&A[(size_t)(m0 + row + asub) * K + k0 + kc8], &Abuf[row * 64]);
        }
        #pragma unroll
        for (int i = 0; i < BN / 32; ++i) {
            int row = brow_base + i * 8;
            gl_lds16(&B[(size_t)(n0 + row + asub) * K + k0 + kc8], &Bbuf[row * 64]);
        }
        __syncthreads();
        #pragma unroll
        for (int kk = 0; kk < 2; ++kk) {
            s16x8 af[4], bf[NREP];
            #pragma unroll
            for (int mf = 0; mf < 4; ++mf)
                af[mf] = *(const s16x8*)&Abuf[(wr * 64 + mf * 16 + l15) * 64 + kk * 32 + lg * 8];
            #pragma unroll
            for (int nf = 0; nf < NREP; ++nf)
                bf[nf] = *(const s16x8*)&Bbuf[(wc * (BN / 2) + nf * 16 + l15) * 64 + kk * 32 + lg * 8];
            #pragma unroll
            for (int mf = 0; mf < 4; ++mf)
                #pragma unroll
                for (int nf = 0; nf < NREP; ++nf)
                    acc[mf][nf] = __builtin_amdgcn_mfma_f32_16x16x32_bf16(af[mf], bf[nf], acc[mf][nf], 0, 0, 0);
        }
        __syncthreads();
    }

    if (WMODE == 0) {
        float bv[NREP];
        #pragma unroll
        for (int nf = 0; nf < NREP; ++nf) bv[nf] = bias[n0 + wc * (BN / 2) + nf * 16 + l15];
        #pragma unroll
        for (int mf = 0; mf < 4; ++mf)
            #pragma unroll
            for (int r = 0; r < 4; ++r) {
                int m = m0 + wr * 64 + mf * 16 + lg * 4 + r;
                #pragma unroll
                for (int nf = 0; nf < NREP; ++nf)
                    outf[(size_t)m * N + n0 + wc * (BN / 2) + nf * 16 + l15] = acc[mf][nf][r] + bv[nf];
            }
    } else {
        const int which = n0 >> 9;
        if (which < 2) {
            const int h = ((n0 & 511) + wc * 64) >> 6;
            ushort* dst = (which == 0) ? outq : outk;
            float bv[4];
            #pragma unroll
            for (int nf = 0; nf < 4; ++nf) bv[nf] = bias[n0 + wc * 64 + nf * 16 + l15];
            const float L2T = 13.287712379549449f;  // log2(10000)
            float inv0 = exp2f(-(float)(l15)      * (L2T / 32.f));
            float inv1 = exp2f(-(float)(16 + l15) * (L2T / 32.f));
            #pragma unroll
            for (int mf = 0; mf < 4; ++mf)
                #pragma unroll
                for (int r = 0; r < 4; ++r) {
                    int m = m0 + wr * 64 + mf * 16 + lg * 4 + r;
                    int b = m >> 10, li = m & (LL - 1);
                    int tt = time_ids[b * LL + li];
                    size_t rowbase = (((size_t)(b * HH + h)) * LL + li) * EHD;
                    #pragma unroll
                    for (int nf = 0; nf < 2; ++nf) {
                        float ang = (float)tt * (nf ? inv1 : inv0);
                        float c, s;
                        sincosf(ang, &s, &c);
                        float v1 = acc[mf][nf][r] + bv[nf];
                        float v2 = acc[mf][nf + 2][r] + bv[nf + 2];
                        dst[rowbase + nf * 16 + l15]      = to_bf16(v1 * c - v2 * s);
                        dst[rowbase + 32 + nf * 16 + l15] = to_bf16(v2 * c + v1 * s);
                    }
                }
        } else {
            ushort* T = (ushort*)smem;   // [128][136]
            float bv[4];
            #pragma unroll
            for (int nf = 0; nf < 4; ++nf) bv[nf] = bias[n0 + wc * 64 + nf * 16 + l15];
            #pragma unroll
            for (int mf = 0; mf < 4; ++mf)
                #pragma unroll
                for (int nf = 0; nf < 4; ++nf) {
                    int n = wc * 64 + nf * 16 + l15;
                    int mb = wr * 64 + mf * 16 + lg * 4;
                    ushort4 pk;
                    pk.x = to_bf16(acc[mf][nf][0] + bv[nf]);
                    pk.y = to_bf16(acc[mf][nf][1] + bv[nf]);
                    pk.z = to_bf16(acc[mf][nf][2] + bv[nf]);
                    pk.w = to_bf16(acc[mf][nf][3] + bv[nf]);
                    *(ushort4*)&T[n * 136 + mb] = pk;
                }
            __syncthreads();
            const int b = m0 >> 10, li0 = m0 & (LL - 1);
            const int hbase = (n0 & 511) >> 6;
            #pragma unroll
            for (int it = 0; it < 8; ++it) {
                int n = it * 16 + (t >> 4);
                int mc = (t & 15) * 8;
                uint4 val = *(const uint4*)&T[n * 136 + mc];
                int h = hbase + (n >> 6);
                int e = n & 63;
                *(uint4*)&outv[(((size_t)(b * HH + h)) * EHD + e) * LL + li0 + mc] = val;
            }
        }
    }
}

// ---------------------------------------------------------------------------
// MFMA attention, 2-phase double-buffered LDS staging (T3 minimum recipe).
// Block = 4 waves x 16 q-rows. K/V staged via global_load_lds with
// pre-swizzled global source (linear LDS dest, XOR swizzle on ds_read).
// One barrier per K-tile; stage of tile t+1 issued before compute of tile t.
// PB A-fragments built from tables; log2-domain online softmax.
// ---------------------------------------------------------------------------
__global__ __launch_bounds__(256, 3) void attn_mfma(const ushort* __restrict__ qb,
                                                    const ushort* __restrict__ kb,
                                                    const ushort* __restrict__ vt,
                                                    const int* __restrict__ time_ids,
                                                    const float* __restrict__ rel_table,
                                                    const float* __restrict__ post_table,
                                                    ushort* __restrict__ ao)
{
    __shared__ __align__(16) float rt_s[1024];        // pre-scaled by log2(e)
    __shared__ __align__(16) float pt_s[1024];        // raw
    __shared__ __align__(16) int   tid_s[1024];
    __shared__ __align__(16) ushort Kbuf[2][4096];    // [64 krow][64 e] linear
    __shared__ __align__(16) ushort Vbuf[2][4096];    // [64 erow][64 k] linear
    __shared__ __align__(16) ushort Ps[4][1024];      // per-wave P, swizzled

    const int t = threadIdx.x;
    const int lane = t & 63;
    const int w = t >> 6;
    const int l15 = lane & 15, lg = lane >> 4;
    const int bh = blockIdx.x, b = bh >> 3, h = bh & 7;
    const int wq0 = blockIdx.y * 64 + w * 16;

    const float L2E = 1.4426950408889634f;
    for (int i = t; i < NBUCK; i += 256) {
        rt_s[i] = rel_table[h * NBUCK + i] * L2E;
        pt_s[i] = post_table[h * NBUCK + i];
    }
    const int* tid_b = time_ids + b * LL;
    #pragma unroll
    for (int i = 0; i < 4; ++i) tid_s[i * 256 + t] = tid_b[i * 256 + t];

    const ushort* qpan = qb + (size_t)bh * LL * EHD;
    const ushort* kpan = kb + (size_t)bh * LL * EHD;
    const ushort* vpan = vt + (size_t)bh * EHD * LL;

    s16x8 qf[2];
    #pragma unroll
    for (int ec = 0; ec < 2; ++ec)
        qf[ec] = *(const s16x8*)&qpan[(size_t)(wq0 + l15) * EHD + ec * 32 + lg * 8];

    int4 tq4 = *(const int4*)&tid_b[wq0 + lg * 4];
    const int tqC[4] = {tq4.x + 511, tq4.y + 511, tq4.z + 511, tq4.w + 511};
    const int tqA = tid_b[wq0 + l15] + 511;

    // staging geometry: wave w stages rows w*8+srow and w*8+32+srow
    const int srow = lane >> 3;          // 0..7
    const int sswz = (lane & 7) ^ srow;  // inverse-swizzled 16B chunk in row

    #define STAGE(BUF, K0)                                                        \
        do {                                                                      \
            int r0 = w * 8 + srow;                                                \
            gl_lds16(&kpan[(size_t)((K0) + r0) * EHD + sswz * 8], &Kbuf[BUF][w * 8 * 64]);       \
            gl_lds16(&vpan[(size_t)r0 * LL + (K0) + sswz * 8],    &Vbuf[BUF][w * 8 * 64]);       \
            gl_lds16(&kpan[(size_t)((K0) + r0 + 32) * EHD + sswz * 8], &Kbuf[BUF][(32 + w * 8) * 64]); \
            gl_lds16(&vpan[(size_t)(r0 + 32) * LL + (K0) + sswz * 8],  &Vbuf[BUF][(32 + w * 8) * 64]); \
        } while (0)

    float mrow[4], drow[4];
    f32x4 acc1[4], acc2[4];
    #pragma unroll
    for (int r = 0; r < 4; ++r) { mrow[r] = -1e30f; drow[r] = 0.f; }
    #pragma unroll
    for (int ei = 0; ei < 4; ++ei) {
        acc1[ei] = {0.f, 0.f, 0.f, 0.f};
        acc2[ei] = {0.f, 0.f, 0.f, 0.f};
    }

    ushort* ps = Ps[w];

    STAGE(0, 0);
    __syncthreads();   // tables + tile 0 ready (barrier drains vmcnt)

    for (int kt = 0; kt < 16; ++kt) {
        const int cur = kt & 1;
        const int k0 = kt * 64;
        if (kt < 15) STAGE(cur ^ 1, k0 + 64);   // async, lands during compute

        const char* Kc = (const char*)Kbuf[cur];
        const char* Vc = (const char*)Vbuf[cur];

        // ---- QK^T ----
        f32x4 sc[4];
        #pragma unroll
        for (int ci = 0; ci < 4; ++ci) sc[ci] = {0.f, 0.f, 0.f, 0.f};
        __builtin_amdgcn_s_setprio(1);
        #pragma unroll
        for (int ec = 0; ec < 2; ++ec)
            #pragma unroll
            for (int ci = 0; ci < 4; ++ci) {
                int row = ci * 16 + l15;
                s16x8 kf = *(const s16x8*)(Kc + row * 128 +
                                           ((ec * 64 + lg * 16) ^ ((row & 7) << 4)));
                sc[ci] = __builtin_amdgcn_mfma_f32_16x16x32_bf16(qf[ec], kf, sc[ci], 0, 0, 0);
            }
        __builtin_amdgcn_s_setprio(0);

        // ---- V fragments (shared by PB and P passes) ----
        s16x8 vf[4][2];
        #pragma unroll
        for (int ei = 0; ei < 4; ++ei)
            #pragma unroll
            for (int kk = 0; kk < 2; ++kk) {
                int row = ei * 16 + l15;
                vf[ei][kk] = *(const s16x8*)(Vc + row * 128 +
                                             ((kk * 64 + lg * 16) ^ ((row & 7) << 4)));
            }

        // ---- PB pass: A-fragments straight from tables ----
        #pragma unroll
        for (int kk = 0; kk < 2; ++kk) {
            int4 ta = *(const int4*)&tid_s[k0 + kk * 32 + lg * 8];
            int4 tb = *(const int4*)&tid_s[k0 + kk * 32 + lg * 8 + 4];
            int tk8[8] = {ta.x, ta.y, ta.z, ta.w, tb.x, tb.y, tb.z, tb.w};
            s16x8 pb;
            #pragma unroll
            for (int j = 0; j < 8; ++j)
                pb[j] = (short)to_bf16(pt_s[tqA - tk8[j]]);
            __builtin_amdgcn_s_setprio(1);
            #pragma unroll
            for (int ei = 0; ei < 4; ++ei)
                acc2[ei] = __builtin_amdgcn_mfma_f32_16x16x32_bf16(pb, vf[ei][kk], acc2[ei], 0, 0, 0);
            __builtin_amdgcn_s_setprio(0);
        }

        // ---- rel bias (log2 domain) ----
        int tkC[4];
        #pragma unroll
        for (int ci = 0; ci < 4; ++ci) tkC[ci] = tid_s[k0 + ci * 16 + l15];
        #pragma unroll
        for (int ci = 0; ci < 4; ++ci)
            #pragma unroll
            for (int r = 0; r < 4; ++r)
                sc[ci][r] = sc[ci][r] * 0.18033688011111793f + rt_s[tqC[r] - tkC[ci]];

        // ---- online softmax (base 2), P -> wave-private LDS ----
        #pragma unroll
        for (int r = 0; r < 4; ++r) {
            float mx = fmaxf(fmaxf(sc[0][r], sc[1][r]), fmaxf(sc[2][r], sc[3][r]));
            #pragma unroll
            for (int d = 1; d < 16; d <<= 1) mx = fmaxf(mx, __shfl_xor(mx, d));
            float mnew = fmaxf(mrow[r], mx);
            float fs = exp2f(mrow[r] - mnew);
            mrow[r] = mnew;
            float rsum = 0.f;
            #pragma unroll
            for (int ci = 0; ci < 4; ++ci) {
                float p = exp2f(sc[ci][r] - mnew);
                sc[ci][r] = p;
                rsum += p;
            }
            #pragma unroll
            for (int d = 1; d < 16; d <<= 1) rsum += __shfl_xor(rsum, d);
            drow[r] = drow[r] * fs + rsum;
            #pragma unroll
            for (int ei = 0; ei < 4; ++ei) acc1[ei][r] *= fs;
            int row = lg * 4 + r;
            #pragma unroll
            for (int ci = 0; ci < 4; ++ci)
                *(ushort*)((char*)ps + row * 128 + ((ci * 32 + l15 * 2) ^ ((row & 7) << 4)))
                    = to_bf16(sc[ci][r]);
        }

        // ---- P @ V ----
        #pragma unroll
        for (int kk = 0; kk < 2; ++kk) {
            s16x8 af = *(const s16x8*)((const char*)ps + l15 * 128 +
                                       ((kk * 64 + lg * 16) ^ ((l15 & 7) << 4)));
            __builtin_amdgcn_s_setprio(1);
            #pragma unroll
            for (int ei = 0; ei < 4; ++ei)
                acc1[ei] = __builtin_amdgcn_mfma_f32_16x16x32_bf16(af, vf[ei][kk], acc1[ei], 0, 0, 0);
            __builtin_amdgcn_s_setprio(0);
        }

        __syncthreads();   // drains vmcnt (next tile staged) + LDS reads done
    }

    #pragma unroll
    for (int ei = 0; ei < 4; ++ei) {
        #pragma unroll
        for (int r = 0; r < 4; ++r) {
            int row = wq0 + lg * 4 + r;
            int col = h * EHD + ei * 16 + l15;
            ao[(size_t)(b * LL + row) * DIMD + col] = to_bf16(acc1[ei][r] / drow[r] + acc2[ei][r]);
        }
    }
}

extern "C" void kernel_launch(void* const* d_in, const int* in_sizes, int n_in,
                              void* d_out, int out_size, void* d_ws, size_t ws_size,
                              hipStream_t stream)
{
    const float* x        = (const float*)d_in[0];
    const int*   time_ids = (const int*)d_in[2];
    const float* W_in     = (const float*)d_in[3];
    const float* b_in     = (const float*)d_in[4];
    const float* W_out    = (const float*)d_in[5];
    const float* b_out    = (const float*)d_in[6];
    const float* rel_t    = (const float*)d_in[7];
    const float* post_t   = (const float*)d_in[8];
    float* out = (float*)d_out;

    ushort* wsu = (ushort*)d_ws;
    ushort* xb  = wsu;
    ushort* wib = xb + XN;
    ushort* wob = wib + WIN;
    ushort* qbf = wob + WON;
    ushort* kbf = qbf + XN;
    ushort* vtb = kbf + XN;
    ushort* aob = vtb + XN;

    cvt_bf16<<<3072, 256, 0, stream>>>(x, W_in, W_out, xb, wib, wob);
    mfma_gemm<128, 1><<<dim3(32, 12), 256, 0, stream>>>(xb, wib, b_in,
                                                        nullptr, qbf, kbf, vtb,
                                                        time_ids,
                                                        BB * LL, 3 * DIMD, DIMD);
    attn_mfma<<<dim3(32, 16), 256, 0, stream>>>(qbf, kbf, vtb, time_ids,
                                                rel_t, post_t, aob);
    mfma_gemm<64, 0><<<dim3(32, 8), 256, 0, stream>>>(aob, wob, b_out,
                                                      out, nullptr, nullptr, nullptr,
                                                      nullptr,
                                                      BB * LL, DIMD, DIMD);
}